// Round 5
// baseline (1199.256 us; speedup 1.0000x reference)
//
#include <hip/hip_runtime.h>
#include <math.h>

namespace {
constexpr int Kc = 1024;   // num_embeddings
constexpr int Dd = 64;     // embedding_dim

// numpy pairwise_sum of squares, n=64, exact numpy op order:
//   tmp[d] = fl(a[d]*a[d]) elementwise (rounded BEFORE summing -> contract off)
//   r[j]=tmp[j]; for i=8..56 step 8: r[j]+=tmp[i+j];
//   res = ((r0+r1)+(r2+r3)) + ((r4+r5)+(r6+r7))
__device__ inline float np_sumsq64(const float* __restrict__ a) {
#pragma clang fp contract(off)
    float r[8];
    #pragma unroll
    for (int j = 0; j < 8; ++j) r[j] = a[j] * a[j];
    #pragma unroll
    for (int i = 8; i < 64; i += 8) {
        #pragma unroll
        for (int j = 0; j < 8; ++j) {
            float s = a[i + j] * a[i + j];   // rounded square
            r[j] = r[j] + s;                 // no FMA fusion (contract off)
        }
    }
    return ((r[0] + r[1]) + (r[2] + r[3])) + ((r[4] + r[5]) + (r[6] + r[7]));
}

// ---- pre: ee[k] (bitwise numpy order), hist zero, emb interleave-transpose --
// emb_il as float4 array: [16 d4][1024 k] -> f4 idx = d4*1024 + k holds
// e[k][4*d4 .. 4*d4+3].
__global__ void k_ee(const float* __restrict__ emb, float* __restrict__ ee,
                     float* __restrict__ emb_il, unsigned int* __restrict__ hist) {
    const int k = blockIdx.x * blockDim.x + threadIdx.x;
    const float* row = emb + (size_t)k * Dd;
    float xl[64];
    #pragma unroll
    for (int d = 0; d < 64; ++d) xl[d] = row[d];
    ee[k] = np_sumsq64(xl);
    hist[k] = 0u;
    #pragma unroll
    for (int d = 0; d < 64; ++d)
        emb_il[(size_t)(d >> 2) * 4096 + k * 4 + (d & 3)] = xl[d];
}

// ---- pre: xx[px] = ||x_px||^2, bitwise numpy order (own kernel so k_main
// never holds a 64-float per-lane array -> no spill pressure) ----------------
__global__ __launch_bounds__(256) void k_xx(const float* __restrict__ inputs,
                                            float* __restrict__ xxg) {
    const int px = blockIdx.x * 256 + threadIdx.x;
    const int b = px >> 10, hw = px & 1023;
    const float* xin = inputs + (size_t)b * 65536 + hw;   // coalesced per d
    float x[64];
    #pragma unroll
    for (int d = 0; d < 64; ++d) x[d] = xin[d * 1024];
    xxg[px] = np_sumsq64(x);
}

// ---- main: entry-per-lane, e via LDS per-lane ds_read_b128, x via s_load ----
// Block = 256 thr (4 waves), 64 pixels; wave w owns pixels [16w,16w+16).
// Codebook streamed as 16 chunks of 64 entries (16 KB interleaved [d4][k][f4]),
// double-buffered, reg-staged. Lane = entry: per d4-step ONE ds_read_b128
// (contiguous 16B/lane, conflict-free) feeds 64 FMAs; the x operand is
// wave-uniform (addresses from readfirstlane(wave)+blockIdx -> s_load, scalar
// pipe, v1's proven path). Pipe budget/CU (4 blocks,16 waves): DS ~61k cyc,
// VALU wall ~150k cyc/SIMD, scalar ~18k -> VALU-bound.
// amdgpu_waves_per_eu(4,4): pins allocator target (v2-v5 lesson: backend
// chases 8 waves/EU -> 64 VGPR -> spills; state here ~90 VGPR, cap 128).
// Numerics identical to v1: per-entry single-acc sequential fmaf d=0..63
// (d4 asc, .x.y.z.w); dist = fmaf(-2, g, xx+ee); argmin via monotone-packed
// (dist,idx) u64 min -> exact first-index, order-independent.
__global__ __launch_bounds__(256) __attribute__((amdgpu_waves_per_eu(4, 4)))
void k_main(const float* __restrict__ inputs, const float* __restrict__ emb,
            const float* __restrict__ emb_il, const float* __restrict__ ee_g,
            const float* __restrict__ xxg,
            float* __restrict__ quant, float* __restrict__ enc,
            float* __restrict__ idx_out, unsigned int* __restrict__ hist,
            float* __restrict__ partials)
{
    __shared__ float4 sbuf[2][1024];              // 2 x 16 KB chunk [d4][lane]
    __shared__ unsigned long long skey[64];

    const int tid = threadIdx.x;
    const int wu  = __builtin_amdgcn_readfirstlane(tid >> 6);  // uniform wave id
    const int l   = tid & 63;                                  // lane = entry
    const int blk = blockIdx.x;
    const int b   = blk >> 4;
    const int hw0 = (blk & 15) << 6;

    // wave-uniform bases for this wave's 16 pixels (all-scalar derivation)
    const float* __restrict__ xw  = inputs + (size_t)b * 65536 + hw0 + (wu << 4);
    const float* __restrict__ xxw = xxg + (blk << 6) + (wu << 4);

    // stage chunk 0: thread covers d4 = wu + 4j, lane l (coalesced 1KB/instr)
    {
        const float4* __restrict__ g = (const float4*)emb_il;
        #pragma unroll
        for (int j = 0; j < 4; ++j) {
            const int d4 = wu + (j << 2);
            sbuf[0][(d4 << 6) + l] = g[(d4 << 10) + l];
        }
    }
    __syncthreads();

    unsigned long long key[16];
    #pragma unroll
    for (int p = 0; p < 16; ++p) key[p] = ~0ULL;

    float4* __restrict__ encb = (float4*)enc + (size_t)blk * 16384;

    #pragma unroll 1
    for (int c = 0; c < 16; ++c) {
        const int cur = c & 1;

        // issue next-chunk global loads EARLY (hide under FMAs)
        float4 n0, n1, n2, n3;
        if (c < 15) {
            const float4* __restrict__ g = (const float4*)emb_il;
            const int gi = ((c + 1) << 6) + l;
            n0 = g[((wu     ) << 10) + gi];
            n1 = g[((wu +  4) << 10) + gi];
            n2 = g[((wu +  8) << 10) + gi];
            n3 = g[((wu + 12) << 10) + gi];
        }

        const float eev = ee_g[(c << 6) + l];     // per-lane, coalesced, L2

        float acc[16];
        #pragma unroll
        for (int p = 0; p < 16; ++p) acc[p] = 0.f;

        const float4* __restrict__ sb = sbuf[cur];
        #pragma unroll
        for (int d4 = 0; d4 < 16; ++d4) {
            const float4 e4 = sb[(d4 << 6) + l];           // ds_read_b128
            const float* __restrict__ xr = xw + (d4 << 2) * 1024;  // uniform
            #pragma unroll
            for (int p = 0; p < 16; ++p) acc[p] = fmaf(xr[p],        e4.x, acc[p]);
            #pragma unroll
            for (int p = 0; p < 16; ++p) acc[p] = fmaf(xr[1024 + p], e4.y, acc[p]);
            #pragma unroll
            for (int p = 0; p < 16; ++p) acc[p] = fmaf(xr[2048 + p], e4.z, acc[p]);
            #pragma unroll
            for (int p = 0; p < 16; ++p) acc[p] = fmaf(xr[3072 + p], e4.w, acc[p]);
        }

        const int kme = (c << 6) + l;             // this lane's entry id
        #pragma unroll
        for (int p = 0; p < 16; ++p) {
            const float A    = xxw[p] + eev;      // one rounding (as v1)
            const float dist = fmaf(-2.f, acc[p], A);   // one rounding (as v1)
            unsigned int ub = __float_as_uint(dist);
            ub = (ub & 0x80000000u) ? ~ub : (ub | 0x80000000u);   // monotone map
            const unsigned long long cand =
                ((unsigned long long)ub << 32) | (unsigned int)kme;
            key[p] = (cand < key[p]) ? cand : key[p];
        }

        // enc zero-fill: 4 float4/thread/chunk (256 KB per block total)
        {
            float4* z4 = encb + (c << 10) + tid;
            const float4 z{0.f, 0.f, 0.f, 0.f};
            z4[0] = z; z4[256] = z; z4[512] = z; z4[768] = z;
        }

        // write staged chunk into the other buffer (after compute; buffer
        // cur^1 was last read in iter c-1, separated by that iter's barrier)
        if (c < 15) {
            float4* __restrict__ s = sbuf[cur ^ 1];
            s[((wu     ) << 6) + l] = n0;
            s[((wu +  4) << 6) + l] = n1;
            s[((wu +  8) << 6) + l] = n2;
            s[((wu + 12) << 6) + l] = n3;
        }
        __syncthreads();
    }

    // cross-lane exact argmin per pixel: u64-min butterfly (6 steps)
    unsigned long long mykey = ~0ULL;
    #pragma unroll
    for (int p = 0; p < 16; ++p) {
        unsigned long long k2 = key[p];
        #pragma unroll
        for (int m = 32; m > 0; m >>= 1) {
            const unsigned long long o = __shfl_xor(k2, m, 64);
            k2 = (o < k2) ? o : k2;
        }
        mykey = (l == p) ? k2 : mykey;            // lane p keeps pixel p's key
    }
    if (l < 16) skey[(wu << 4) + l] = mykey;
    __syncthreads();   // also drains enc zero-fill stores

    if (tid < 64) {    // coalesced epilogue: pixel = lane (v1-proven path)
        const unsigned long long kk = skey[l];
        const int bi = (int)(kk & 0xffffffffu);
        unsigned int ub = (unsigned int)(kk >> 32);
        ub = (ub & 0x80000000u) ? (ub & 0x7fffffffu) : ~ub;   // mono inverse
        const float bd = __uint_as_float(ub);                  // bit-exact dist
        const int n = (blk << 6) + l;

        // quantized output: gather codebook row, store NCHW (coalesced per d)
        {
            const float4* ebq = (const float4*)(emb + ((size_t)bi << 6));
            float* qout = quant + (size_t)b * 65536 + hw0 + l;
            #pragma unroll
            for (int i = 0; i < 16; ++i) {
                const float4 v = ebq[i];
                qout[(i * 4 + 0) * 1024] = v.x;
                qout[(i * 4 + 1) * 1024] = v.y;
                qout[(i * 4 + 2) * 1024] = v.z;
                qout[(i * 4 + 3) * 1024] = v.w;
            }
        }

        idx_out[n] = (float)bi;
        atomicAdd(hist + bi, 1u);
        enc[((size_t)n << 10) + bi] = 1.0f;   // one-hot into zeroed row

        // loss partial: dist_min == ||x - e*||^2
        float v = bd;
        #pragma unroll
        for (int off = 32; off > 0; off >>= 1) v += __shfl_down(v, off, 64);
        if (l == 0) partials[blk] = v;
    }
}

// ---- final: perplexity from histogram, loss from partials (1 sync total) ----
__global__ __launch_bounds__(1024) void k_fin(
    const unsigned int* __restrict__ hist, const float* __restrict__ partials,
    float* __restrict__ loss_out, float* __restrict__ perp_out)
{
    __shared__ double sent[16];
    __shared__ double spar[16];
    const int tid = threadIdx.x;

    double pv = (double)hist[tid] * (1.0 / 65536.0);
    double e = pv * log(pv + 1e-10);
    double s = (double)partials[tid];

    #pragma unroll
    for (int off = 32; off > 0; off >>= 1) {
        e += __shfl_down(e, off, 64);
        s += __shfl_down(s, off, 64);
    }
    if ((tid & 63) == 0) { sent[tid >> 6] = e; spar[tid >> 6] = s; }
    __syncthreads();

    if (tid == 0) {
        double ent = 0.0, sum = 0.0;
        #pragma unroll
        for (int w = 0; w < 16; ++w) { ent += sent[w]; sum += spar[w]; }
        double perp = exp(-ent);
        double mean = sum * (1.0 / 4194304.0);   // sum ||x-e||^2 / (N*D)
        double loss = 1.25 * mean + 0.1 * (1024.0 - perp) / 1024.0;
        loss_out[0] = (float)loss;
        perp_out[0] = (float)perp;
    }
}
} // namespace

extern "C" void kernel_launch(void* const* d_in, const int* in_sizes, int n_in,
                              void* d_out, int out_size, void* d_ws, size_t ws_size,
                              hipStream_t stream)
{
    const float* inputs = (const float*)d_in[0];   // [64,64,32,32] fp32
    const float* emb    = (const float*)d_in[1];   // [1024,64] fp32
    float* out = (float*)d_out;

    float* loss_out = out;                            // [1]
    float* quant    = out + 1;                        // [64,64,32,32]
    float* perp_out = out + 1 + 4194304;              // [1]
    float* enc      = out + 2 + 4194304;              // [65536,1024]
    float* idx_out  = out + 2 + 4194304 + 67108864;   // [65536,1]

    unsigned int* hist = (unsigned int*)d_ws;         // [1024] u32
    float* partials    = (float*)d_ws + 1024;         // [1024] f32 (overwritten)
    float* ee          = (float*)d_ws + 2048;         // [1024] f32
    float* emb_il      = (float*)d_ws + 3072;         // [65536] f32 (256 KB)
    float* xxg         = (float*)d_ws + 3072 + 65536; // [65536] f32 (256 KB)

    k_ee<<<Kc / 256, 256, 0, stream>>>(emb, ee, emb_il, hist);
    k_xx<<<65536 / 256, 256, 0, stream>>>(inputs, xxg);
    k_main<<<65536 / 64, 256, 0, stream>>>(inputs, emb, emb_il, ee, xxg,
                                           quant, enc, idx_out, hist, partials);
    k_fin<<<1, 1024, 0, stream>>>(hist, partials, loss_out, perp_out);
}

// Round 6
// 1090.387 us; speedup vs baseline: 1.0998x; 1.0998x over previous
//
#include <hip/hip_runtime.h>
#include <math.h>

namespace {
constexpr int Kc = 1024;   // num_embeddings
constexpr int Dd = 64;     // embedding_dim

// numpy pairwise_sum of squares, n=64, exact numpy op order:
//   tmp[d] = fl(a[d]*a[d]) elementwise (rounded BEFORE summing -> contract off)
//   r[j]=tmp[j]; for i=8..56 step 8: r[j]+=tmp[i+j];
//   res = ((r0+r1)+(r2+r3)) + ((r4+r5)+(r6+r7))
__device__ inline float np_sumsq64(const float* __restrict__ a) {
#pragma clang fp contract(off)
    float r[8];
    #pragma unroll
    for (int j = 0; j < 8; ++j) r[j] = a[j] * a[j];
    #pragma unroll
    for (int i = 8; i < 64; i += 8) {
        #pragma unroll
        for (int j = 0; j < 8; ++j) {
            float s = a[i + j] * a[i + j];   // rounded square
            r[j] = r[j] + s;                 // no FMA fusion (contract off)
        }
    }
    return ((r[0] + r[1]) + (r[2] + r[3])) + ((r[4] + r[5]) + (r[6] + r[7]));
}

// ---- pre: ee[k] (bitwise numpy order), hist zero, emb interleave-transpose --
// emb_il as float4 array: [16 d4][1024 k]; f4 idx d4*1024+k holds e[k][4d4..4d4+3]
__global__ void k_ee(const float* __restrict__ emb, float* __restrict__ ee,
                     float* __restrict__ emb_il, unsigned int* __restrict__ hist) {
    const int k = blockIdx.x * blockDim.x + threadIdx.x;
    const float* row = emb + (size_t)k * Dd;
    float xl[64];
    #pragma unroll
    for (int d = 0; d < 64; ++d) xl[d] = row[d];
    ee[k] = np_sumsq64(xl);
    hist[k] = 0u;
    #pragma unroll
    for (int d = 0; d < 64; ++d)
        emb_il[(size_t)(d >> 2) * 4096 + k * 4 + (d & 3)] = xl[d];
}

// ---- pre: xx[px] = ||x_px||^2 bitwise (own kernel: k_main never holds x[64])
__global__ __launch_bounds__(256) void k_xx(const float* __restrict__ inputs,
                                            float* __restrict__ xxg) {
    const int px = blockIdx.x * 256 + threadIdx.x;
    const int b = px >> 10, hw = px & 1023;
    const float* xin = inputs + (size_t)b * 65536 + hw;   // coalesced per d
    float x[64];
    #pragma unroll
    for (int d = 0; d < 64; ++d) x[d] = xin[d * 1024];
    xxg[px] = np_sumsq64(x);
}

// ---- main: entry-per-lane; e via LDS ds_read_b128; x via scalar pipe --------
// DESIGNED FOR <=64 VGPR (v2-v6 lesson: allocator pins ~64 VGPR and spills any
// excess; all prior failures were spill traffic). Peak live state ~55:
//   best[16] + cn[2 packed nibble words] + acc[16] + e4 + addr/misc.
//   - index state is 2 VGPRs, not 32: best entry for lane l is chunk*64+l, so
//     only the 4-bit chunk id per pixel is stored (nibble-packed).
//   - staging (16 VGPR) moved BEFORE compute: does not overlap acc[16]. Safe:
//     barrier of chunk c-1 drained all reads of buf^1. Latency hidden by TLP
//     (4 blocks/CU, barriers desynced across blocks).
//   - xx via s_load into SGPRs (uniform addr), zero VGPR cost.
// Pipe budget/CU/chunk: DS 16w*16*12=3.1k cyc, VALU 4w*~1140*2=9.1k cyc/SIMD,
// scalar 1k loads -> VALU-bound; FMA issue floor ~55 us.
// Numerics identical to v1: per-entry single-acc sequential fmaf d=0..63
// (d4 asc, .x.y.z.w); dist = fmaf(-2, g, xx+ee); per-lane strict < keeps
// earliest chunk (smallest k for that lane); final monotone-packed (dist,idx)
// u64 butterfly -> exact global first-index, order-independent.
__global__ __launch_bounds__(256, 4) void k_main(
    const float* __restrict__ inputs, const float* __restrict__ emb,
    const float* __restrict__ emb_il, const float* __restrict__ ee_g,
    const float* __restrict__ xxg,
    float* __restrict__ quant, float* __restrict__ enc,
    float* __restrict__ idx_out, unsigned int* __restrict__ hist,
    float* __restrict__ partials)
{
    __shared__ float4 sbuf[2][1024];              // 2 x 16 KB chunk [d4][lane]
    __shared__ unsigned long long skey[64];

    const int tid = threadIdx.x;
    const int wu  = __builtin_amdgcn_readfirstlane(tid >> 6);  // uniform wave id
    const int l   = tid & 63;                                  // lane = entry
    const int blk = blockIdx.x;
    const int b   = blk >> 4;
    const int hw0 = (blk & 15) << 6;

    // wave-uniform bases (scalar-derived) for this wave's 16 pixels
    const float* __restrict__ xw  = inputs + (size_t)b * 65536 + hw0 + (wu << 4);
    const float* __restrict__ xxw = xxg + (blk << 6) + (wu << 4);

    // xx for the wave's 16 pixels: uniform addr + const offsets -> SGPRs
    float sxx[16];
    #pragma unroll
    for (int p = 0; p < 16; ++p) sxx[p] = xxw[p];

    // stage chunk 0: wave covers d4 = wu+4j (coalesced 1KB/instr)
    {
        const float4* __restrict__ g = (const float4*)emb_il + l;
        #pragma unroll
        for (int j = 0; j < 4; ++j) {
            const int d4 = wu + (j << 2);
            sbuf[0][(d4 << 6) + l] = g[d4 << 10];
        }
    }
    __syncthreads();

    float best[16];
    unsigned int cn[2] = {0u, 0u};                // 16 x 4-bit chunk ids
    #pragma unroll
    for (int p = 0; p < 16; ++p) best[p] = INFINITY;

    float4* __restrict__ encb = (float4*)enc + (size_t)blk * 16384;

    #pragma unroll 1
    for (int c = 0; c < 16; ++c) {
        const int cur = c & 1;

        // stage chunk c+1 into buf^1 FIRST (no reg overlap with acc);
        // buf^1's chunk-(c-1) reads were drained by the last barrier
        if (c < 15) {
            const float4* __restrict__ g =
                (const float4*)emb_il + ((c + 1) << 6) + l;
            float4 n0 = g[(wu     ) << 10];
            float4 n1 = g[(wu +  4) << 10];
            float4 n2 = g[(wu +  8) << 10];
            float4 n3 = g[(wu + 12) << 10];
            float4* __restrict__ s = sbuf[cur ^ 1];
            s[((wu     ) << 6) + l] = n0;
            s[((wu +  4) << 6) + l] = n1;
            s[((wu +  8) << 6) + l] = n2;
            s[((wu + 12) << 6) + l] = n3;
        }

        const float eev = ee_g[(c << 6) + l];     // per-lane, coalesced, hot

        float acc[16];
        #pragma unroll
        for (int p = 0; p < 16; ++p) acc[p] = 0.f;

        const float4* __restrict__ sb = sbuf[cur];
        #pragma unroll
        for (int d4 = 0; d4 < 16; ++d4) {
            const float4 e4 = sb[(d4 << 6) + l];           // ds_read_b128
            const float* __restrict__ x0 = xw + (d4 << 2) * 1024;  // uniform
            #pragma unroll
            for (int p = 0; p < 16; ++p) acc[p] = fmaf(x0[p],        e4.x, acc[p]);
            #pragma unroll
            for (int p = 0; p < 16; ++p) acc[p] = fmaf(x0[1024 + p], e4.y, acc[p]);
            #pragma unroll
            for (int p = 0; p < 16; ++p) acc[p] = fmaf(x0[2048 + p], e4.z, acc[p]);
            #pragma unroll
            for (int p = 0; p < 16; ++p) acc[p] = fmaf(x0[3072 + p], e4.w, acc[p]);
        }

        #pragma unroll
        for (int p = 0; p < 16; ++p) {
            const float A    = sxx[p] + eev;            // one rounding (as v1)
            const float dist = fmaf(-2.f, acc[p], A);   // one rounding (as v1)
            const bool lt = dist < best[p];   // strict <: earliest chunk kept
            best[p] = lt ? dist : best[p];
            const int sh = (p & 7) << 2;
            const unsigned int t =
                (cn[p >> 3] & ~(0xFu << sh)) | ((unsigned int)c << sh);
            cn[p >> 3] = lt ? t : cn[p >> 3];
        }

        // enc zero-fill: 4 float4/thread/chunk (256 KB per block total)
        {
            float4* z4 = encb + (c << 10) + tid;
            const float4 z{0.f, 0.f, 0.f, 0.f};
            z4[0] = z; z4[256] = z; z4[512] = z; z4[768] = z;
        }

        __syncthreads();
    }

    // cross-lane exact argmin per pixel: u64 (mono-dist, idx) min butterfly
    unsigned long long mykey = ~0ULL;
    #pragma unroll
    for (int p = 0; p < 16; ++p) {
        const int sh = (p & 7) << 2;
        const int kmine = (int)(((cn[p >> 3] >> sh) & 0xFu) << 6) | l;
        unsigned int ub = __float_as_uint(best[p]);
        ub = (ub & 0x80000000u) ? ~ub : (ub | 0x80000000u);   // monotone map
        unsigned long long k2 =
            ((unsigned long long)ub << 32) | (unsigned int)kmine;
        #pragma unroll
        for (int m = 32; m > 0; m >>= 1) {
            const unsigned long long o = __shfl_xor(k2, m, 64);
            k2 = (o < k2) ? o : k2;
        }
        mykey = (l == p) ? k2 : mykey;            // lane p keeps pixel p's key
    }
    if (l < 16) skey[(wu << 4) + l] = mykey;
    __syncthreads();   // also drains enc zero-fill stores

    if (tid < 64) {    // coalesced epilogue: pixel = lane (v1-proven path)
        const unsigned long long kk = skey[l];
        const int bi = (int)(kk & 0xffffffffu);
        unsigned int ub = (unsigned int)(kk >> 32);
        ub = (ub & 0x80000000u) ? (ub & 0x7fffffffu) : ~ub;   // mono inverse
        const float bd = __uint_as_float(ub);                  // bit-exact dist
        const int n = (blk << 6) + l;

        // quantized output: gather codebook row, store NCHW (coalesced per d)
        {
            const float4* ebq = (const float4*)(emb + ((size_t)bi << 6));
            float* qout = quant + (size_t)b * 65536 + hw0 + l;
            #pragma unroll
            for (int i = 0; i < 16; ++i) {
                const float4 v = ebq[i];
                qout[(i * 4 + 0) * 1024] = v.x;
                qout[(i * 4 + 1) * 1024] = v.y;
                qout[(i * 4 + 2) * 1024] = v.z;
                qout[(i * 4 + 3) * 1024] = v.w;
            }
        }

        idx_out[n] = (float)bi;
        atomicAdd(hist + bi, 1u);
        enc[((size_t)n << 10) + bi] = 1.0f;   // one-hot into zeroed row

        // loss partial: dist_min == ||x - e*||^2
        float v = bd;
        #pragma unroll
        for (int off = 32; off > 0; off >>= 1) v += __shfl_down(v, off, 64);
        if (l == 0) partials[blk] = v;
    }
}

// ---- final: perplexity from histogram, loss from partials (1 sync total) ----
__global__ __launch_bounds__(1024) void k_fin(
    const unsigned int* __restrict__ hist, const float* __restrict__ partials,
    float* __restrict__ loss_out, float* __restrict__ perp_out)
{
    __shared__ double sent[16];
    __shared__ double spar[16];
    const int tid = threadIdx.x;

    double pv = (double)hist[tid] * (1.0 / 65536.0);
    double e = pv * log(pv + 1e-10);
    double s = (double)partials[tid];

    #pragma unroll
    for (int off = 32; off > 0; off >>= 1) {
        e += __shfl_down(e, off, 64);
        s += __shfl_down(s, off, 64);
    }
    if ((tid & 63) == 0) { sent[tid >> 6] = e; spar[tid >> 6] = s; }
    __syncthreads();

    if (tid == 0) {
        double ent = 0.0, sum = 0.0;
        #pragma unroll
        for (int w = 0; w < 16; ++w) { ent += sent[w]; sum += spar[w]; }
        double perp = exp(-ent);
        double mean = sum * (1.0 / 4194304.0);   // sum ||x-e||^2 / (N*D)
        double loss = 1.25 * mean + 0.1 * (1024.0 - perp) / 1024.0;
        loss_out[0] = (float)loss;
        perp_out[0] = (float)perp;
    }
}
} // namespace

extern "C" void kernel_launch(void* const* d_in, const int* in_sizes, int n_in,
                              void* d_out, int out_size, void* d_ws, size_t ws_size,
                              hipStream_t stream)
{
    const float* inputs = (const float*)d_in[0];   // [64,64,32,32] fp32
    const float* emb    = (const float*)d_in[1];   // [1024,64] fp32
    float* out = (float*)d_out;

    float* loss_out = out;                            // [1]
    float* quant    = out + 1;                        // [64,64,32,32]
    float* perp_out = out + 1 + 4194304;              // [1]
    float* enc      = out + 2 + 4194304;              // [65536,1024]
    float* idx_out  = out + 2 + 4194304 + 67108864;   // [65536,1]

    unsigned int* hist = (unsigned int*)d_ws;         // [1024] u32
    float* partials    = (float*)d_ws + 1024;         // [1024] f32 (overwritten)
    float* ee          = (float*)d_ws + 2048;         // [1024] f32
    float* emb_il      = (float*)d_ws + 3072;         // [65536] f32 (256 KB)
    float* xxg         = (float*)d_ws + 3072 + 65536; // [65536] f32 (256 KB)

    k_ee<<<Kc / 256, 256, 0, stream>>>(emb, ee, emb_il, hist);
    k_xx<<<65536 / 256, 256, 0, stream>>>(inputs, xxg);
    k_main<<<65536 / 64, 256, 0, stream>>>(inputs, emb, emb_il, ee, xxg,
                                           quant, enc, idx_out, hist, partials);
    k_fin<<<1, 1024, 0, stream>>>(hist, partials, loss_out, perp_out);
}

// Round 7
// 979.568 us; speedup vs baseline: 1.2243x; 1.1131x over previous
//
#include <hip/hip_runtime.h>
#include <math.h>

namespace {
constexpr int Kc = 1024;   // num_embeddings
constexpr int Dd = 64;     // embedding_dim

// numpy pairwise_sum of squares, n=64, exact numpy op order:
//   tmp[d] = fl(a[d]*a[d]) elementwise (rounded BEFORE summing -> contract off)
//   r[j]=tmp[j]; for i=8..56 step 8: r[j]+=tmp[i+j];
//   res = ((r0+r1)+(r2+r3)) + ((r4+r5)+(r6+r7))
__device__ inline float np_sumsq64(const float* __restrict__ a) {
#pragma clang fp contract(off)
    float r[8];
    #pragma unroll
    for (int j = 0; j < 8; ++j) r[j] = a[j] * a[j];
    #pragma unroll
    for (int i = 8; i < 64; i += 8) {
        #pragma unroll
        for (int j = 0; j < 8; ++j) {
            float s = a[i + j] * a[i + j];   // rounded square
            r[j] = r[j] + s;                 // no FMA fusion (contract off)
        }
    }
    return ((r[0] + r[1]) + (r[2] + r[3])) + ((r[4] + r[5]) + (r[6] + r[7]));
}

// ---- pre: ee[k] = np.sum(emb*emb, axis=1) bitwise; also zero hist ----------
__global__ void k_ee(const float* __restrict__ emb, float* __restrict__ ee,
                     unsigned int* __restrict__ hist) {
    const int k = blockIdx.x * blockDim.x + threadIdx.x;
    ee[k] = np_sumsq64(emb + (size_t)k * Dd);
    hist[k] = 0u;
}

// ---- main: 256 blocks x 256 thr = 1024 waves = exactly 1 wave per SIMD ------
// launch_bounds(256,1): occupancy target 1 wave/EU -> VGPR budget 256 (v2-v7
// lesson: 64-VGPR allocator wall appears at >=4-waves/EU targets; here x[64]
// plus pipelined e-loads fit with huge headroom -> no spill possible).
// Waves are fully independent: lane = pixel, no LDS, no barriers, no merge.
// Feed: e-rows loaded as uniform-address float4 VMEM/K$ reads, pipelined by
// the compiler with partial waits (v7 lesson: mixing ds_read + s_load forces
// lgkmcnt(0) full drains -> serialization; here there is NO ds traffic, and
// only 4 waves/CU walk emb in the same order -> cache-friendly).
// Pair-ILP: 2 entries with 2 independent single-acc chains hides the 4-cyc
// FMA dep latency (no TLP at 1 wave/SIMD).
// Numerics identical to v1: k ascending 0..1023, strict < (exact numpy
// first-index); per-entry single-acc sequential fmaf d=0..63;
// dist = fmaf(-2, g, xx+ee[k]).
__global__ __launch_bounds__(256, 1) void k_main(
    const float* __restrict__ inputs, const float* __restrict__ emb,
    const float* __restrict__ ee_g, float* __restrict__ quant,
    float* __restrict__ enc, float* __restrict__ idx_out,
    unsigned int* __restrict__ hist, float* __restrict__ partials)
{
    const int tid = threadIdx.x;
    const int w   = tid >> 6;              // wave id (independent unit)
    const int l   = tid & 63;              // lane = pixel
    const int blk = blockIdx.x;            // 256 blocks -> ~1 per CU
    const int px  = (blk << 8) + (w << 6) + l;
    const int b   = px >> 10;
    const int hw  = px & 1023;

    // x[d] = inputs[b, d, hw]  (coalesced 256B per d across the wave)
    const float* xin = inputs + (size_t)b * 65536 + hw;
    float x[64];
    #pragma unroll
    for (int d = 0; d < 64; ++d) x[d] = xin[d * 1024];
    const float xx = np_sumsq64(x);        // numpy-order fp32 ||x||^2

    // enc zero-fill: this wave owns rows [px0, px0+64) = 256 KB contiguous;
    // 1 float4/lane per 4 entries (256 stores) interleaved under the FMAs
    float4* __restrict__ encz =
        (float4*)enc + ((size_t)((blk << 8) + (w << 6)) << 8) + l;

    float best = INFINITY;
    int   bi   = 0;
    const float4* __restrict__ e4p = (const float4*)emb;   // [1024][16]

    #pragma unroll 1
    for (int k = 0; k < Kc; k += 2) {      // ascending: first-index tie-break
        const float4* __restrict__ E = e4p + (k << 4);
        float g0 = 0.f, g1 = 0.f;          // 2 independent sequential chains
        #pragma unroll
        for (int i = 0; i < 16; ++i) {
            const float4 a = E[i];         // entry k   (uniform addr, cached)
            const float4 c = E[16 + i];    // entry k+1
            g0 = fmaf(x[4*i+0], a.x, g0);
            g0 = fmaf(x[4*i+1], a.y, g0);
            g0 = fmaf(x[4*i+2], a.z, g0);
            g0 = fmaf(x[4*i+3], a.w, g0);
            g1 = fmaf(x[4*i+0], c.x, g1);
            g1 = fmaf(x[4*i+1], c.y, g1);
            g1 = fmaf(x[4*i+2], c.z, g1);
            g1 = fmaf(x[4*i+3], c.w, g1);
        }
        // numpy: dist = fl( fl(xx + ee[k]) - 2*g )  (one rounding each)
        const float A0 = xx + ee_g[k];
        const float A1 = xx + ee_g[k + 1];
        const float d0 = fmaf(-2.f, g0, A0);
        const float d1 = fmaf(-2.f, g1, A1);
        const bool lt0 = d0 < best;        // strict <: earliest k kept
        best = lt0 ? d0 : best;  bi = lt0 ? k : bi;
        const bool lt1 = d1 < best;
        best = lt1 ? d1 : best;  bi = lt1 ? (k + 1) : bi;

        if ((k & 3) == 0) {                // 1 store / 4 entries -> 256 total
            *encz = float4{0.f, 0.f, 0.f, 0.f};
            encz += 64;
        }
    }

    // ---- epilogue: every lane owns its pixel (no merge needed) ----
    // quantized output: gather codebook row, store NCHW (coalesced per d)
    {
        const float4* __restrict__ ebq = (const float4*)(emb + ((size_t)bi << 6));
        float* qout = quant + (size_t)b * 65536 + hw;
        #pragma unroll
        for (int i = 0; i < 16; ++i) {
            const float4 v = ebq[i];
            qout[(i * 4 + 0) * 1024] = v.x;
            qout[(i * 4 + 1) * 1024] = v.y;
            qout[(i * 4 + 2) * 1024] = v.z;
            qout[(i * 4 + 3) * 1024] = v.w;
        }
    }

    idx_out[px] = (float)bi;
    atomicAdd(hist + bi, 1u);
    // one-hot into this wave's own zeroed rows; same-wave same-address store
    // order (zero first, then 1.0f) is program order
    enc[((size_t)px << 10) + bi] = 1.0f;

    // loss partial: dist_min == ||x - e*||^2 ; one partial per wave (1024)
    float v = best;
    #pragma unroll
    for (int off = 32; off > 0; off >>= 1) v += __shfl_down(v, off, 64);
    if (l == 0) partials[(blk << 2) + w] = v;
}

// ---- final: perplexity from histogram, loss from partials (1 sync total) ----
__global__ __launch_bounds__(1024) void k_fin(
    const unsigned int* __restrict__ hist, const float* __restrict__ partials,
    float* __restrict__ loss_out, float* __restrict__ perp_out)
{
    __shared__ double sent[16];
    __shared__ double spar[16];
    const int tid = threadIdx.x;

    double pv = (double)hist[tid] * (1.0 / 65536.0);
    double e = pv * log(pv + 1e-10);
    double s = (double)partials[tid];

    #pragma unroll
    for (int off = 32; off > 0; off >>= 1) {
        e += __shfl_down(e, off, 64);
        s += __shfl_down(s, off, 64);
    }
    if ((tid & 63) == 0) { sent[tid >> 6] = e; spar[tid >> 6] = s; }
    __syncthreads();

    if (tid == 0) {
        double ent = 0.0, sum = 0.0;
        #pragma unroll
        for (int w = 0; w < 16; ++w) { ent += sent[w]; sum += spar[w]; }
        double perp = exp(-ent);
        double mean = sum * (1.0 / 4194304.0);   // sum ||x-e||^2 / (N*D)
        double loss = 1.25 * mean + 0.1 * (1024.0 - perp) / 1024.0;
        loss_out[0] = (float)loss;
        perp_out[0] = (float)perp;
    }
}
} // namespace

extern "C" void kernel_launch(void* const* d_in, const int* in_sizes, int n_in,
                              void* d_out, int out_size, void* d_ws, size_t ws_size,
                              hipStream_t stream)
{
    const float* inputs = (const float*)d_in[0];   // [64,64,32,32] fp32
    const float* emb    = (const float*)d_in[1];   // [1024,64] fp32
    float* out = (float*)d_out;

    float* loss_out = out;                            // [1]
    float* quant    = out + 1;                        // [64,64,32,32]
    float* perp_out = out + 1 + 4194304;              // [1]
    float* enc      = out + 2 + 4194304;              // [65536,1024]
    float* idx_out  = out + 2 + 4194304 + 67108864;   // [65536,1]

    unsigned int* hist = (unsigned int*)d_ws;         // [1024] u32
    float* partials    = (float*)d_ws + 1024;         // [1024] f32 (overwritten)
    float* ee          = (float*)d_ws + 2048;         // [1024] f32

    k_ee<<<Kc / 256, 256, 0, stream>>>(emb, ee, hist);
    k_main<<<256, 256, 0, stream>>>(inputs, emb, ee, quant, enc, idx_out,
                                    hist, partials);
    k_fin<<<1, 1024, 0, stream>>>(hist, partials, loss_out, perp_out);
}

// Round 8
// 826.584 us; speedup vs baseline: 1.4509x; 1.1851x over previous
//
#include <hip/hip_runtime.h>
#include <math.h>

namespace {
constexpr int Kc = 1024;   // num_embeddings
constexpr int Dd = 64;     // embedding_dim

// numpy pairwise_sum of squares, n=64, exact numpy op order:
//   tmp[d] = fl(a[d]*a[d]) elementwise (rounded BEFORE summing -> contract off)
//   r[j]=tmp[j]; for i=8..56 step 8: r[j]+=tmp[i+j];
//   res = ((r0+r1)+(r2+r3)) + ((r4+r5)+(r6+r7))
__device__ inline float np_sumsq64(const float* __restrict__ a) {
#pragma clang fp contract(off)
    float r[8];
    #pragma unroll
    for (int j = 0; j < 8; ++j) r[j] = a[j] * a[j];
    #pragma unroll
    for (int i = 8; i < 64; i += 8) {
        #pragma unroll
        for (int j = 0; j < 8; ++j) {
            float s = a[i + j] * a[i + j];   // rounded square
            r[j] = r[j] + s;                 // no FMA fusion (contract off)
        }
    }
    return ((r[0] + r[1]) + (r[2] + r[3])) + ((r[4] + r[5]) + (r[6] + r[7]));
}

// ---- pre: ee[k] = np.sum(emb*emb, axis=1) bitwise; also zero hist ----------
__global__ void k_ee(const float* __restrict__ emb, float* __restrict__ ee,
                     unsigned int* __restrict__ hist) {
    const int k = blockIdx.x * blockDim.x + threadIdx.x;
    ee[k] = np_sumsq64(emb + (size_t)k * Dd);
    hist[k] = 0u;
}

// ---- main: 512 blocks x 256 thr = 2048 waves = 2 waves/SIMD -----------------
// v8 diagnosis: VGPR=48 + no scratch + FETCH tiny => compiler RE-LOADS x[d]
// from cache inside the k-loop (remat-by-reload; legal since inputs is const
// __restrict__) instead of keeping x[64] live -- that is the 7-round "64-VGPR
// wall". Fix #1: pin x[64] with volatile asm (non-rematerializable def) so the
// values MUST stay in VGPRs. Fix #2: k-split per wave pair (half codebook
// each) -> 2048 waves = 2/SIMD for TLP to hide the uniform E-row load latency.
// Block covers 128 pixels: wave w: pixel group g=w>>1 (64 px, lane=pixel),
// k-half kh=w&1 (k in [kh*512,(kh+1)*512) ascending).
// Numerics identical to v1: per-entry single-acc sequential fmaf d=0..63
// (f4 .x.y.z.w order); dist = fmaf(-2, g, xx+ee[k]); strict < ascending within
// half = first-index per half; cross-half u64 (mono-dist,idx) min = exact
// global first-index (disjoint ranges: equal dist -> smaller k = half 0).
__global__ __launch_bounds__(256, 2) void k_main(
    const float* __restrict__ inputs, const float* __restrict__ emb,
    const float* __restrict__ ee_g, float* __restrict__ quant,
    float* __restrict__ enc, float* __restrict__ idx_out,
    unsigned int* __restrict__ hist, float* __restrict__ partials)
{
    __shared__ unsigned long long skey[4][64];   // [wave][lane]

    const int tid = threadIdx.x;
    const int w   = tid >> 6;              // wave id 0..3
    const int l   = tid & 63;              // lane
    const int grp = w >> 1;                // pixel group (0,1)
    const int kh  = w & 1;                 // codebook half
    const int blk = blockIdx.x;            // 0..511
    const int px  = (blk << 7) + (grp << 6) + l;
    const int b   = px >> 10;
    const int hw  = px & 1023;

    // x[d] = inputs[b, d, hw]  (coalesced 256B per d across the wave)
    const float* xin = inputs + (size_t)b * 65536 + hw;
    float x[64];
    #pragma unroll
    for (int d = 0; d < 64; ++d) x[d] = xin[d * 1024];
    // PIN: volatile asm def is non-rematerializable -> x stays in VGPRs for
    // the whole k-loop (defeats the compiler's remat-by-reload escape hatch)
    #pragma unroll
    for (int d = 0; d < 64; ++d) asm volatile("" : "+v"(x[d]));

    const float xx = np_sumsq64(x);        // numpy-order fp32 ||x||^2

    // enc zero-fill: block owns rows [blk*128, blk*128+128) = 512 KB;
    // 128 float4/thread, one store every other pair-iteration
    float4* __restrict__ encz = (float4*)enc + (size_t)blk * 32768 + tid;

    float best = INFINITY;
    int   bi   = 0;
    const int k0 = kh << 9;                // 0 or 512
    const float4* __restrict__ e4p = (const float4*)emb;   // [1024][16]

    #pragma unroll 2
    for (int i = 0; i < 256; ++i) {        // 256 pairs = 512 entries, ascending
        const int k = k0 + (i << 1);
        const float4* __restrict__ E = e4p + ((size_t)k << 4);
        float g0 = 0.f, g1 = 0.f;          // 2 independent sequential chains
        #pragma unroll
        for (int q = 0; q < 16; ++q) {
            const float4 a = E[q];         // entry k   (uniform addr, cached)
            const float4 c = E[16 + q];    // entry k+1
            g0 = fmaf(x[4*q+0], a.x, g0);
            g0 = fmaf(x[4*q+1], a.y, g0);
            g0 = fmaf(x[4*q+2], a.z, g0);
            g0 = fmaf(x[4*q+3], a.w, g0);
            g1 = fmaf(x[4*q+0], c.x, g1);
            g1 = fmaf(x[4*q+1], c.y, g1);
            g1 = fmaf(x[4*q+2], c.z, g1);
            g1 = fmaf(x[4*q+3], c.w, g1);
        }
        // numpy: dist = fl( fl(xx + ee[k]) - 2*g )  (one rounding each)
        const float A0 = xx + ee_g[k];
        const float A1 = xx + ee_g[k + 1];
        const float d0 = fmaf(-2.f, g0, A0);
        const float d1 = fmaf(-2.f, g1, A1);
        const bool lt0 = d0 < best;        // strict <: earliest k kept
        best = lt0 ? d0 : best;  bi = lt0 ? k : bi;
        const bool lt1 = d1 < best;
        best = lt1 ? d1 : best;  bi = lt1 ? (k + 1) : bi;

        if ((i & 1) == 0) {                // 128 zero-stores interleaved
            *encz = float4{0.f, 0.f, 0.f, 0.f};
            encz += 256;
        }
    }

    // publish (dist, idx) as monotone-packed u64 (min == lex (dist asc, k asc))
    {
        unsigned int ub = __float_as_uint(best);
        ub = (ub & 0x80000000u) ? ~ub : (ub | 0x80000000u);
        skey[w][l] = ((unsigned long long)ub << 32) | (unsigned int)bi;
    }
    __syncthreads();   // skeys visible; enc zero-fill drained (vmcnt0+barrier)

    if (tid < 128) {   // 2 full waves; pixel = blk*128 + tid (coalesced)
        const int g2 = tid >> 6;           // pixel group
        const int l2 = tid & 63;
        const unsigned long long ka = skey[(g2 << 1) + 0][l2];
        const unsigned long long kb = skey[(g2 << 1) + 1][l2];
        const unsigned long long kk = (kb < ka) ? kb : ka;
        const int bi2 = (int)(kk & 0xffffffffu);
        unsigned int ub = (unsigned int)(kk >> 32);
        ub = (ub & 0x80000000u) ? (ub & 0x7fffffffu) : ~ub;   // mono inverse
        const float bd = __uint_as_float(ub);                  // bit-exact dist
        const int px2 = (blk << 7) + tid;
        const int b2  = px2 >> 10;
        const int hw2 = px2 & 1023;

        // quantized output: gather codebook row, store NCHW (coalesced per d)
        {
            const float4* __restrict__ ebq =
                (const float4*)(emb + ((size_t)bi2 << 6));
            float* qout = quant + (size_t)b2 * 65536 + hw2;
            #pragma unroll
            for (int q = 0; q < 16; ++q) {
                const float4 v = ebq[q];
                qout[(q * 4 + 0) * 1024] = v.x;
                qout[(q * 4 + 1) * 1024] = v.y;
                qout[(q * 4 + 2) * 1024] = v.z;
                qout[(q * 4 + 3) * 1024] = v.w;
            }
        }

        idx_out[px2] = (float)bi2;
        atomicAdd(hist + bi2, 1u);
        enc[((size_t)px2 << 10) + bi2] = 1.0f;   // one-hot into zeroed row

        // loss partial: dist_min == ||x - e*||^2 ; per 64-px group (as v1)
        float v = bd;
        #pragma unroll
        for (int off = 32; off > 0; off >>= 1) v += __shfl_down(v, off, 64);
        if (l2 == 0) partials[(blk << 1) + g2] = v;
    }
}

// ---- final: perplexity from histogram, loss from partials (1 sync total) ----
__global__ __launch_bounds__(1024) void k_fin(
    const unsigned int* __restrict__ hist, const float* __restrict__ partials,
    float* __restrict__ loss_out, float* __restrict__ perp_out)
{
    __shared__ double sent[16];
    __shared__ double spar[16];
    const int tid = threadIdx.x;

    double pv = (double)hist[tid] * (1.0 / 65536.0);
    double e = pv * log(pv + 1e-10);
    double s = (double)partials[tid];

    #pragma unroll
    for (int off = 32; off > 0; off >>= 1) {
        e += __shfl_down(e, off, 64);
        s += __shfl_down(s, off, 64);
    }
    if ((tid & 63) == 0) { sent[tid >> 6] = e; spar[tid >> 6] = s; }
    __syncthreads();

    if (tid == 0) {
        double ent = 0.0, sum = 0.0;
        #pragma unroll
        for (int w = 0; w < 16; ++w) { ent += sent[w]; sum += spar[w]; }
        double perp = exp(-ent);
        double mean = sum * (1.0 / 4194304.0);   // sum ||x-e||^2 / (N*D)
        double loss = 1.25 * mean + 0.1 * (1024.0 - perp) / 1024.0;
        loss_out[0] = (float)loss;
        perp_out[0] = (float)perp;
    }
}
} // namespace

extern "C" void kernel_launch(void* const* d_in, const int* in_sizes, int n_in,
                              void* d_out, int out_size, void* d_ws, size_t ws_size,
                              hipStream_t stream)
{
    const float* inputs = (const float*)d_in[0];   // [64,64,32,32] fp32
    const float* emb    = (const float*)d_in[1];   // [1024,64] fp32
    float* out = (float*)d_out;

    float* loss_out = out;                            // [1]
    float* quant    = out + 1;                        // [64,64,32,32]
    float* perp_out = out + 1 + 4194304;              // [1]
    float* enc      = out + 2 + 4194304;              // [65536,1024]
    float* idx_out  = out + 2 + 4194304 + 67108864;   // [65536,1]

    unsigned int* hist = (unsigned int*)d_ws;         // [1024] u32
    float* partials    = (float*)d_ws + 1024;         // [1024] f32 (overwritten)
    float* ee          = (float*)d_ws + 2048;         // [1024] f32

    k_ee<<<Kc / 256, 256, 0, stream>>>(emb, ee, hist);
    k_main<<<512, 256, 0, stream>>>(inputs, emb, ee, quant, enc, idx_out,
                                    hist, partials);
    k_fin<<<1, 1024, 0, stream>>>(hist, partials, loss_out, perp_out);
}